// Round 21
// baseline (142.379 us; speedup 1.0000x reference)
//
#include <hip/hip_runtime.h>
#include <hip/hip_bf16.h>
#include <cstdint>
#include <cstddef>

// ---------------------------------------------------------------------------
// MultiHeadAttention (B=2, S=2048, D=1024, H=16, DK=64), fp32 in/out,
// bf16 MFMA internal compute. THREE dispatches:
// 1) gemm_qkv: reads fp32 X/W directly (reg-staged cvt into swizzled LDS);
//    Q/K as C^T = W X^T -> fragment-major Qf/Kf; V -> per-head-transposed Vf;
//    Q pre-scaled log2e/8.
// 2) flash_reg (R18-proven, FROZEN): paired q-slices, 4 kv-quarter waves,
//    no LDS staging / no kv-loop barriers, in-register P, defer-max.
// 3) gemm_o: At (bf16, global_load_lds) x Wo (fp32, reg-staged cvt) -> fp32.
// ---------------------------------------------------------------------------

#define B_ 2
#define S_ 2048
#define D_ 1024
#define H_ 16
#define DK_ 64
#define QSCALE 0.1803368801111244f   /* (1/8)*log2(e): softmax in exp2 domain */

typedef __attribute__((ext_vector_type(8))) short bf16x8;
typedef __attribute__((ext_vector_type(4))) float f32x4;
typedef __attribute__((ext_vector_type(16))) float f32x16;
typedef __attribute__((ext_vector_type(4))) unsigned short u16x4;
typedef __attribute__((ext_vector_type(4))) float float4v;
typedef __attribute__((ext_vector_type(2))) unsigned int u32x2;
typedef __attribute__((ext_vector_type(4))) unsigned int u32x4;
typedef __attribute__((ext_vector_type(2))) int i32x2;

__device__ __forceinline__ unsigned short f2bf(float f) {
  unsigned int u = __float_as_uint(f);
  u += 0x7FFFu + ((u >> 16) & 1u);
  return (unsigned short)(u >> 16);
}
__device__ __forceinline__ unsigned int cvt_pk_bf16(float lo, float hi) {
  unsigned int r;
  asm("v_cvt_pk_bf16_f32 %0, %1, %2" : "=v"(r) : "v"(lo), "v"(hi));
  return r;
}
// value held by lane^32, via permlane32_swap (VALU pipe, no LDS)
__device__ __forceinline__ float partner32f(float x, int hi5) {
  int xi = __float_as_int(x);
  i32x2 r = __builtin_amdgcn_permlane32_swap(xi, xi, false, false);
  return __int_as_float(hi5 ? r[0] : r[1]);
}
__device__ __forceinline__ unsigned int partner32u(unsigned int x, int hi5) {
  i32x2 r = __builtin_amdgcn_permlane32_swap((int)x, (int)x, false, false);
  return (unsigned int)(hi5 ? r[0] : r[1]);
}
// swizzled read of a [R][64]-ushort LDS tile (128B rows): byte ^= ((row&7)<<4)
__device__ __forceinline__ bf16x8 lds_read_sw64(const unsigned short* base, int row, int col) {
  int P = (row * 64 + col) * 2;
  int X = P ^ ((row & 7) << 4);
  return *(const bf16x8*)((const char*)base + X);
}
// load 8 fp32, convert to bf16x8 packed dwords (for swizzled LDS staging)
__device__ __forceinline__ u32x4 ld_cvt8(const float* __restrict__ p) {
  float4v a0 = *(const float4v*)p;
  float4v a1 = *(const float4v*)(p + 4);
  u32x4 o = {cvt_pk_bf16(a0[0], a0[1]), cvt_pk_bf16(a0[2], a0[3]),
             cvt_pk_bf16(a1[0], a1[1]), cvt_pk_bf16(a1[2], a1[3])};
  return o;
}

// ---------------------------- fused QKV GEMM (fp32 in) ---------------------
// Fragment-major layouts (consumed by flash_reg):
//   Qf/Kf[bh][s32][f][hi5][ql][e]: elem = Q[s32*32+ql][f*16+hi5*8+e]
//   Vf[bh][kv32][dt][half][hi5][ql][e]: elem = V[kv32*32+half*16+hi5*8+e][dt*32+ql]
// z=0/1 (Q/K): C^T[d][s] = W X^T -> u16x4 stores. z=2 (V): X W^T.
// Staging: fp32 source loads + cvt_pk -> ds_write_b128 at the same XOR-
// swizzled dest bytes the reads expect (write/read swizzles match).
__global__ __launch_bounds__(256) void gemm_qkv(
    const float* __restrict__ Xq, const float* __restrict__ Xk,
    const float* __restrict__ Xv, const float* __restrict__ Wq,
    const float* __restrict__ Wk, const float* __restrict__ Wv,
    const float* __restrict__ bq, const float* __restrict__ bk,
    const float* __restrict__ bv, unsigned short* __restrict__ Qf,
    unsigned short* __restrict__ Kf, unsigned short* __restrict__ Vf) {
  const int z = blockIdx.z;
  const float* A = z == 0 ? Wq : z == 1 ? Wk : Xv;
  const float* W = z == 0 ? Xq : z == 1 ? Xk : Wv;
  const float* bias = z == 0 ? bq : z == 1 ? bk : bv;
  const int K = D_;

  __shared__ __align__(16) unsigned short As[128 * 64];
  __shared__ __align__(16) unsigned short Bs[128 * 64];
  const int tid  = threadIdx.x;
  const int lane = tid & 63;
  const int m0 = (z == 2 ? blockIdx.x : blockIdx.y) * 128;
  const int n0 = (z == 2 ? blockIdx.y : blockIdx.x) * 128;
  const int wr = ((tid >> 6) >> 1) * 64;
  const int wc = ((tid >> 6) & 1) * 64;
  const int lr = lane & 15;
  const int lk = (lane >> 4) * 8;
  f32x4 acc[4][4] = {};

  int dstX[4], srow[4], scolu[4];
#pragma unroll
  for (int i = 0; i < 4; ++i) {
    int X = tid * 16 + i * 4096;
    int P = X ^ (((X >> 7) & 7) << 4);
    dstX[i] = X;
    srow[i] = P >> 7;
    scolu[i] = (P & 127) >> 1;
  }

  for (int k0 = 0; k0 < K; k0 += 64) {
    __syncthreads();
#pragma unroll
    for (int i = 0; i < 4; ++i) {
      const float* gA = A + (size_t)(m0 + srow[i]) * K + k0 + scolu[i];
      const float* gB = W + (size_t)(n0 + srow[i]) * K + k0 + scolu[i];
      *(u32x4*)((char*)As + dstX[i]) = ld_cvt8(gA);
      *(u32x4*)((char*)Bs + dstX[i]) = ld_cvt8(gB);
    }
    __syncthreads();
#pragma unroll
    for (int kk = 0; kk < 2; ++kk) {
      bf16x8 a[4], b[4];
#pragma unroll
      for (int m = 0; m < 4; ++m)
        a[m] = lds_read_sw64(As, wr + m * 16 + lr, kk * 32 + lk);
#pragma unroll
      for (int n = 0; n < 4; ++n)
        b[n] = lds_read_sw64(Bs, wc + n * 16 + lr, kk * 32 + lk);
#pragma unroll
      for (int m = 0; m < 4; ++m)
#pragma unroll
        for (int n = 0; n < 4; ++n)
          acc[m][n] = __builtin_amdgcn_mfma_f32_16x16x32_bf16(a[m], b[n], acc[m][n], 0, 0, 0);
    }
  }

  const int rbase = (lane >> 4) * 4;
  if (z == 2) {
#pragma unroll
    for (int m = 0; m < 4; ++m)
#pragma unroll
      for (int n = 0; n < 4; ++n) {
        int col = n0 + wc + n * 16 + lr;            // d-global
        float bvv = bias[col];
        int row0 = m0 + wr + m * 16 + rbase;        // s-global (4 consecutive)
        int bb = row0 >> 11, sr = row0 & 2047;
        int h = col >> 6, dk = col & 63;
        int kv32 = sr >> 5, half = (sr >> 4) & 1, hi5p = (sr >> 3) & 1, e0 = sr & 7;
        int dt = dk >> 5, qlp = dk & 31;
        u16x4 o;
#pragma unroll
        for (int r = 0; r < 4; ++r) o[r] = f2bf(acc[m][n][r] + bvv);
        size_t idx = ((((size_t)(bb * H_ + h) * 64 + kv32) * 2 + dt) * 2 + half) * 512
                     + (hi5p * 32 + qlp) * 8 + e0;
        *(u16x4*)(Vf + idx) = o;
      }
  } else {
    unsigned short* Cout = z == 0 ? Qf : Kf;
    const float scale = z == 0 ? QSCALE : 1.0f;
#pragma unroll
    for (int m = 0; m < 4; ++m)
#pragma unroll
      for (int n = 0; n < 4; ++n) {
        int col = n0 + wc + n * 16 + lr;            // s-global
        int drow0 = m0 + wr + m * 16 + rbase;       // d-global (4 consecutive)
        float4v bv4 = *(const float4v*)(bias + drow0);
        int h = drow0 >> 6, dk = drow0 & 63;
        int f = dk >> 4, hi5p = (dk >> 3) & 1, e0 = dk & 7;
        int bb = col >> 11, sr = col & 2047;
        int s32 = sr >> 5, qlp = sr & 31;
        u16x4 o;
#pragma unroll
        for (int r = 0; r < 4; ++r) o[r] = f2bf((acc[m][n][r] + bv4[r]) * scale);
        size_t base = (((size_t)(bb * H_ + h) * 64 + s32) * 4 + f) * 512
                      + (hi5p * 32 + qlp) * 8 + e0;
        *(u16x4*)(Cout + base) = o;
      }
  }
}

// ---------------------------- O GEMM (64x128 tile, fp32 W) -----------------
__global__ __launch_bounds__(256) void gemm_o(const unsigned short* __restrict__ A,
                                              const float* __restrict__ W,
                                              const float* __restrict__ bias,
                                              float* __restrict__ C,
                                              int M, int N, int K) {
  __shared__ __align__(16) unsigned short As[64 * 64];
  __shared__ __align__(16) unsigned short Bs[128 * 64];
  const int tid  = threadIdx.x;
  const int lane = tid & 63;
  const int m0 = blockIdx.x * 64;
  const int n0 = blockIdx.y * 128;
  const int wr = ((tid >> 6) >> 1) * 32;
  const int wc = ((tid >> 6) & 1) * 64;
  const int lr = lane & 15;
  const int lk = (lane >> 4) * 8;
  f32x4 acc[2][4] = {};

  int dstX[4], srow[4], scolu[4];
#pragma unroll
  for (int i = 0; i < 4; ++i) {
    int X = tid * 16 + i * 4096;
    int P = X ^ (((X >> 7) & 7) << 4);
    dstX[i] = X;
    srow[i] = P >> 7;
    scolu[i] = (P & 127) >> 1;
  }

  for (int k0 = 0; k0 < K; k0 += 64) {
    __syncthreads();
#pragma unroll
    for (int i = 0; i < 2; ++i) {   // At is bf16: async global->LDS
      const unsigned short* gA = A + (size_t)(m0 + srow[i]) * K + k0 + scolu[i];
      __builtin_amdgcn_global_load_lds((const __attribute__((address_space(1))) void*)gA,
          (__attribute__((address_space(3))) void*)((char*)As + dstX[i]), 16, 0, 0);
    }
#pragma unroll
    for (int i = 0; i < 4; ++i) {   // Wo is fp32: reg-stage + cvt
      const float* gB = W + (size_t)(n0 + srow[i]) * K + k0 + scolu[i];
      *(u32x4*)((char*)Bs + dstX[i]) = ld_cvt8(gB);
    }
    __syncthreads();
#pragma unroll
    for (int kk = 0; kk < 2; ++kk) {
      bf16x8 a[2], b[4];
#pragma unroll
      for (int m = 0; m < 2; ++m)
        a[m] = lds_read_sw64(As, wr + m * 16 + lr, kk * 32 + lk);
#pragma unroll
      for (int n = 0; n < 4; ++n)
        b[n] = lds_read_sw64(Bs, wc + n * 16 + lr, kk * 32 + lk);
#pragma unroll
      for (int m = 0; m < 2; ++m)
#pragma unroll
        for (int n = 0; n < 4; ++n)
          acc[m][n] = __builtin_amdgcn_mfma_f32_16x16x32_bf16(a[m], b[n], acc[m][n], 0, 0, 0);
    }
  }

  const int rbase = (lane >> 4) * 4;
#pragma unroll
  for (int m = 0; m < 2; ++m)
#pragma unroll
    for (int n = 0; n < 4; ++n) {
      int col = n0 + wc + n * 16 + lr;
      float bvv = bias[col];
#pragma unroll
      for (int r = 0; r < 4; ++r) {
        int row = m0 + wr + m * 16 + rbase + r;
        C[(size_t)row * N + col] = acc[m][n][r] + bvv;
      }
    }
}

// ---------------------------- flash attention (reg, FROZEN R18) ------------
// Grid: (32, H, B), 256 threads = 4 waves. Block owns paired q-slices
// (63-bx, bx), 32 q-rows each. Wave kq processes kv windows w == kq (mod 4),
// loading K/V fragments as coalesced b128 from fragment-major Kf/Vf.
// No LDS staging, no kv-loop barriers, no prefetch (R17: spills), no XCD
// remap (R14/R15: L2-BW loss), no unpairing (R20: occupancy tail).
__global__ __launch_bounds__(256, 4) void flash_reg(const unsigned short* __restrict__ Qf,
                                                    const unsigned short* __restrict__ Kf,
                                                    const unsigned short* __restrict__ Vf,
                                                    unsigned short* __restrict__ Op) {
  __shared__ float scr[3 * 64 * 34];   // 26112 B merge scratch

  const int tid  = threadIdx.x;
  const int lane = tid & 63;
  const int kq   = tid >> 6;
  const int bx = blockIdx.x;
  const int h  = blockIdx.y;
  const int b  = blockIdx.z;
  const int ql = lane & 31;
  const int hi5 = lane >> 5;
  const int bh = b * H_ + h;
  const size_t basebs = (size_t)b * S_ * D_;
  const int hoff = h * DK_;

  const unsigned short* Qb = Qf + (size_t)bh * 131072 + lane * 8;
  const unsigned short* Kb = Kf + (size_t)bh * 131072 + lane * 8;
  const unsigned short* Vb = Vf + (size_t)bh * 131072 + lane * 8;

  for (int s = 0; s < 2; ++s) {
    const int j = s == 0 ? 63 - bx : bx;   // q-slice index (32 rows)
    const int q0 = j * 32;
    const int qglob = q0 + ql;

    bf16x8 qf4[4];
    {
      const unsigned short* qp_ = Qb + (size_t)j * 2048;
#pragma unroll
      for (int f = 0; f < 4; ++f) qf4[f] = *(const bf16x8*)(qp_ + f * 512);
    }

    float m_r = -1e30f;
    float l_r = 0.f;
    f32x16 out0 = {};   // d = (g&3)+8*(g>>2)+4*hi5
    f32x16 out1 = {};   // d = 32 + same

    for (int w = kq; w <= j; w += 4) {
      const unsigned short* kp_ = Kb + (size_t)w * 2048;
      bf16x8 kf0 = *(const bf16x8*)(kp_);
      bf16x8 kf1 = *(const bf16x8*)(kp_ + 512);
      bf16x8 kf2 = *(const bf16x8*)(kp_ + 1024);
      bf16x8 kf3 = *(const bf16x8*)(kp_ + 1536);

      f32x16 sc = {};
      __builtin_amdgcn_s_setprio(1);
      sc = __builtin_amdgcn_mfma_f32_32x32x16_bf16(kf0, qf4[0], sc, 0, 0, 0);
      sc = __builtin_amdgcn_mfma_f32_32x32x16_bf16(kf1, qf4[1], sc, 0, 0, 0);
      sc = __builtin_amdgcn_mfma_f32_32x32x16_bf16(kf2, qf4[2], sc, 0, 0, 0);
      sc = __builtin_amdgcn_mfma_f32_32x32x16_bf16(kf3, qf4[3], sc, 0, 0, 0);
      __builtin_amdgcn_s_setprio(0);

      // V fragment loads issued early: latency hides under softmax
      const unsigned short* vp_ = Vb + (size_t)w * 2048;
      bf16x8 vf00 = *(const bf16x8*)(vp_);          // dt0 half0
      bf16x8 vf01 = *(const bf16x8*)(vp_ + 512);    // dt0 half1
      bf16x8 vf10 = *(const bf16x8*)(vp_ + 1024);   // dt1 half0
      bf16x8 vf11 = *(const bf16x8*)(vp_ + 1536);   // dt1 half1

      if (w == j) {   // diagonal: causal mask
#pragma unroll
        for (int g = 0; g < 16; ++g) {
          int kvg = w * 32 + (g & 3) + 8 * (g >> 2) + 4 * hi5;
          if (kvg > qglob) sc[g] = -1e30f;
        }
      }

      float pm = sc[0];
#pragma unroll
      for (int g = 1; g < 16; ++g) pm = fmaxf(pm, sc[g]);
      pm = fmaxf(pm, partner32f(pm, hi5));

      if (!__all(pm - m_r <= 8.0f)) {   // defer-max (2^8 headroom)
        float mnew = fmaxf(m_r, pm);
        float scl = __builtin_exp2f(m_r - mnew);
        l_r *= scl;
#pragma unroll
        for (int g = 0; g < 16; ++g) { out0[g] *= scl; out1[g] *= scl; }
        m_r = mnew;
      }

      float l_add = 0.f;
#define PV_HALF(HALF, VF0, VF1)                                                \
      {                                                                        \
        const int g0 = (HALF) * 8;                                             \
        float p0 = __builtin_exp2f(sc[g0 + 0] - m_r);                          \
        float p1 = __builtin_exp2f(sc[g0 + 1] - m_r);                          \
        float p2 = __builtin_exp2f(sc[g0 + 2] - m_r);                          \
        float p3 = __builtin_exp2f(sc[g0 + 3] - m_r);                          \
        float p4 = __builtin_exp2f(sc[g0 + 4] - m_r);                          \
        float p5 = __builtin_exp2f(sc[g0 + 5] - m_r);                          \
        float p6 = __builtin_exp2f(sc[g0 + 6] - m_r);                          \
        float p7 = __builtin_exp2f(sc[g0 + 7] - m_r);                          \
        l_add += ((p0 + p1) + (p2 + p3)) + ((p4 + p5) + (p6 + p7));            \
        unsigned int u0 = cvt_pk_bf16(p0, p1);                                 \
        unsigned int u1 = cvt_pk_bf16(p2, p3);                                 \
        unsigned int u2 = cvt_pk_bf16(p4, p5);                                 \
        unsigned int u3 = cvt_pk_bf16(p6, p7);                                 \
        unsigned int ta = hi5 ? u0 : u2, tb = hi5 ? u1 : u3;                   \
        unsigned int ra = partner32u(ta, hi5);                                 \
        unsigned int rb = partner32u(tb, hi5);                                 \
        u32x4 pw = {hi5 ? ra : u0, hi5 ? rb : u1,                              \
                    hi5 ? u2 : ra, hi5 ? u3 : rb};                             \
        bf16x8 pf = __builtin_bit_cast(bf16x8, pw);                            \
        out0 = __builtin_amdgcn_mfma_f32_32x32x16_bf16(VF0, pf, out0, 0, 0, 0);\
        out1 = __builtin_amdgcn_mfma_f32_32x32x16_bf16(VF1, pf, out1, 0, 0, 0);\
      }
      __builtin_amdgcn_s_setprio(1);
      PV_HALF(0, vf00, vf10);
      PV_HALF(1, vf01, vf11);
      __builtin_amdgcn_s_setprio(0);
#undef PV_HALF

      l_add += partner32f(l_add, hi5);
      l_r += l_add;
    }

    // ---- merge the 4 kv-quarter partials ----
    __syncthreads();
    if (kq != 0) {
      float* p = scr + ((size_t)(kq - 1) * 64 + lane) * 34;
#pragma unroll
      for (int g = 0; g < 16; ++g) { p[g] = out0[g]; p[16 + g] = out1[g]; }
      p[32] = m_r;
      p[33] = l_r;
    }
    __syncthreads();
    if (kq == 0) {
      float mA = m_r, lA = l_r;
#pragma unroll
      for (int j3 = 0; j3 < 3; ++j3) {
        const float* p = scr + ((size_t)j3 * 64 + lane) * 34;
        float mj = p[32], lj = p[33];
        float mM = fmaxf(mA, mj);
        float s0 = __builtin_exp2f(mA - mM);
        float s1 = __builtin_exp2f(mj - mM);
#pragma unroll
        for (int g = 0; g < 16; ++g) {
          out0[g] = out0[g] * s0 + p[g] * s1;
          out1[g] = out1[g] * s0 + p[16 + g] * s1;
        }
        lA = lA * s0 + lj * s1;
        mA = mM;
      }
      float rcp = 1.0f / lA;
      unsigned short* orow = Op + basebs + (size_t)qglob * D_ + hoff;
#pragma unroll
      for (int i = 0; i < 4; ++i) {
        u32x2 o0 = {cvt_pk_bf16(out0[4 * i + 0] * rcp, out0[4 * i + 1] * rcp),
                    cvt_pk_bf16(out0[4 * i + 2] * rcp, out0[4 * i + 3] * rcp)};
        *(u32x2*)(orow + 8 * i + 4 * hi5) = o0;
        u32x2 o1 = {cvt_pk_bf16(out1[4 * i + 0] * rcp, out1[4 * i + 1] * rcp),
                    cvt_pk_bf16(out1[4 * i + 2] * rcp, out1[4 * i + 3] * rcp)};
        *(u32x2*)(orow + 32 + 8 * i + 4 * hi5) = o1;
      }
    }
    __syncthreads();   // scratch reads done before next slice's writes
  }
}

// ---------------------------- launch ---------------------------------------
extern "C" void kernel_launch(void* const* d_in, const int* in_sizes, int n_in,
                              void* d_out, int out_size, void* d_ws, size_t ws_size,
                              hipStream_t stream) {
  const float* q  = (const float*)d_in[0];
  const float* k  = (const float*)d_in[1];
  const float* v  = (const float*)d_in[2];
  // d_in[3] = causal mask (tril) -- semantics hard-coded in flash_reg
  const float* Wq = (const float*)d_in[4];
  const float* bq = (const float*)d_in[5];
  const float* Wk = (const float*)d_in[6];
  const float* bk = (const float*)d_in[7];
  const float* Wv = (const float*)d_in[8];
  const float* bv = (const float*)d_in[9];
  const float* Wo = (const float*)d_in[10];
  const float* bo = (const float*)d_in[11];

  const int MSD = B_ * S_;     // 4096 rows
  unsigned short* ws = (unsigned short*)d_ws;
  unsigned short* Qf  = ws;                      // fragment-major layouts
  unsigned short* Kf  = Qf + (size_t)MSD * D_;
  unsigned short* Vf  = Kf + (size_t)MSD * D_;
  unsigned short* At  = Vf + (size_t)MSD * D_;   // attention out, row-major

  dim3 gqkv(MSD / 128, D_ / 128, 3);   // (32, 8, 3) = 768 blocks
  gemm_qkv<<<gqkv, 256, 0, stream>>>(q, k, v, Wq, Wk, Wv,
                                     bq, bk, bv, Qf, Kf, Vf);

  dim3 ga(32, H_, B_);                 // 1024 blocks x 4 waves, paired slices
  flash_reg<<<ga, 256, 0, stream>>>(Qf, Kf, Vf, At);

  dim3 go(MSD / 64, D_ / 128);         // (64, 8) = 512 blocks
  gemm_o<<<go, 256, 0, stream>>>(At, Wo, bo, (float*)d_out, MSD, D_, D_);
}

// Round 22
// 129.414 us; speedup vs baseline: 1.1002x; 1.1002x over previous
//
#include <hip/hip_runtime.h>
#include <hip/hip_bf16.h>
#include <cstdint>
#include <cstddef>

// ---------------------------------------------------------------------------
// MultiHeadAttention (B=2, S=2048, D=1024, H=16, DK=64), fp32 in/out,
// bf16 MFMA internal compute.  R18-proven configuration (best: 129.5 us).
// cvt (ONE fused dispatch) -> QKV GEMM (grid.z; XOR-swizzled LDS via
// global_load_lds; Q/K as C^T = W X^T with vectorized fragment-major stores;
// V per-head transposed; Q pre-scaled log2e/8) -> flash attention "reg"
// (paired q-slices, 4 kv-quarter waves, no LDS staging / no kv-loop
// barriers, in-register P, defer-max) -> O GEMM 64x128 (fp32 out).
// Falsified (do not retry): K-prefetch (R17: VGPR spill), XCD remap
// (R14/R15: L2-BW loss), unpaired grid (R20: occupancy tail), min-waves
// launch_bounds (R19: VGPR cap 64->40 + spill), fp32 sync reg-staging
// (R21: exposed latency, gemm 32->90 us).
// ---------------------------------------------------------------------------

#define B_ 2
#define S_ 2048
#define D_ 1024
#define H_ 16
#define DK_ 64
#define QSCALE 0.1803368801111244f   /* (1/8)*log2(e): softmax in exp2 domain */

typedef __attribute__((ext_vector_type(8))) short bf16x8;
typedef __attribute__((ext_vector_type(4))) float f32x4;
typedef __attribute__((ext_vector_type(16))) float f32x16;
typedef __attribute__((ext_vector_type(4))) unsigned short u16x4;
typedef __attribute__((ext_vector_type(4))) float float4v;
typedef __attribute__((ext_vector_type(2))) unsigned int u32x2;
typedef __attribute__((ext_vector_type(4))) unsigned int u32x4;
typedef __attribute__((ext_vector_type(2))) int i32x2;

__device__ __forceinline__ unsigned short f2bf(float f) {
  unsigned int u = __float_as_uint(f);
  u += 0x7FFFu + ((u >> 16) & 1u);
  return (unsigned short)(u >> 16);
}
__device__ __forceinline__ unsigned int cvt_pk_bf16(float lo, float hi) {
  unsigned int r;
  asm("v_cvt_pk_bf16_f32 %0, %1, %2" : "=v"(r) : "v"(lo), "v"(hi));
  return r;
}
// value held by lane^32, via permlane32_swap (VALU pipe, no LDS)
__device__ __forceinline__ float partner32f(float x, int hi5) {
  int xi = __float_as_int(x);
  i32x2 r = __builtin_amdgcn_permlane32_swap(xi, xi, false, false);
  return __int_as_float(hi5 ? r[0] : r[1]);
}
__device__ __forceinline__ unsigned int partner32u(unsigned int x, int hi5) {
  i32x2 r = __builtin_amdgcn_permlane32_swap((int)x, (int)x, false, false);
  return (unsigned int)(hi5 ? r[0] : r[1]);
}
// swizzled read of a [R][64]-ushort LDS tile (128B rows): byte ^= ((row&7)<<4)
__device__ __forceinline__ bf16x8 lds_read_sw64(const unsigned short* base, int row, int col) {
  int P = (row * 64 + col) * 2;
  int X = P ^ ((row & 7) << 4);
  return *(const bf16x8*)((const char*)base + X);
}

// ---------------------------- fp32 -> bf16 convert (single dispatch) -------
// Blocks [0,12288) -> q/k/v (4096 each); [12288,16384) -> 4 weights (1024 ea).
__global__ __launch_bounds__(256) void cvt_all(
    const float* __restrict__ q, const float* __restrict__ k,
    const float* __restrict__ v, const float* __restrict__ w0,
    const float* __restrict__ w1, const float* __restrict__ w2,
    const float* __restrict__ w3, unsigned short* __restrict__ dq,
    unsigned short* __restrict__ dk, unsigned short* __restrict__ dv,
    unsigned short* __restrict__ dw0, unsigned short* __restrict__ dw1,
    unsigned short* __restrict__ dw2, unsigned short* __restrict__ dw3) {
  int bid = blockIdx.x;
  const float* src;
  unsigned short* dst;
  int blk;
  if (bid < 12288) {
    int t = bid >> 12;
    blk = bid & 4095;
    src = t == 0 ? q : t == 1 ? k : v;
    dst = t == 0 ? dq : t == 1 ? dk : dv;
  } else {
    int t = (bid - 12288) >> 10;
    blk = (bid - 12288) & 1023;
    src = t == 0 ? w0 : t == 1 ? w1 : t == 2 ? w2 : w3;
    dst = t == 0 ? dw0 : t == 1 ? dw1 : t == 2 ? dw2 : dw3;
  }
  size_t i = ((size_t)blk * 256 + threadIdx.x) * 4;
  float4v x = *(const float4v*)(src + i);
  u16x4 o;
  o[0] = f2bf(x[0]); o[1] = f2bf(x[1]); o[2] = f2bf(x[2]); o[3] = f2bf(x[3]);
  *(u16x4*)(dst + i) = o;
}

// ---------------------------- fused QKV GEMM -------------------------------
// Fragment-major layouts (consumed by flash_reg):
//   Qf/Kf[bh][s32][f][hi5][ql][e]: elem = Q[s32*32+ql][f*16+hi5*8+e]
//   Vf[bh][kv32][dt][half][hi5][ql][e]: elem = V[kv32*32+half*16+hi5*8+e][dt*32+ql]
// z=0/1 (Q/K): compute C^T[d][s] = W X^T -> u16x4 stores. z=2 (V): X W^T.
__global__ __launch_bounds__(256) void gemm_qkv(
    const unsigned short* __restrict__ Xq, const unsigned short* __restrict__ Xk,
    const unsigned short* __restrict__ Xv, const unsigned short* __restrict__ Wq,
    const unsigned short* __restrict__ Wk, const unsigned short* __restrict__ Wv,
    const float* __restrict__ bq, const float* __restrict__ bk,
    const float* __restrict__ bv, unsigned short* __restrict__ Qf,
    unsigned short* __restrict__ Kf, unsigned short* __restrict__ Vf) {
  const int z = blockIdx.z;
  const unsigned short* A = z == 0 ? Wq : z == 1 ? Wk : Xv;
  const unsigned short* W = z == 0 ? Xq : z == 1 ? Xk : Wv;
  const float* bias = z == 0 ? bq : z == 1 ? bk : bv;
  const int K = D_;

  __shared__ __align__(16) unsigned short As[128 * 64];
  __shared__ __align__(16) unsigned short Bs[128 * 64];
  const int tid  = threadIdx.x;
  const int lane = tid & 63;
  const int m0 = (z == 2 ? blockIdx.x : blockIdx.y) * 128;
  const int n0 = (z == 2 ? blockIdx.y : blockIdx.x) * 128;
  const int wr = ((tid >> 6) >> 1) * 64;
  const int wc = ((tid >> 6) & 1) * 64;
  const int lr = lane & 15;
  const int lk = (lane >> 4) * 8;
  f32x4 acc[4][4] = {};

  int dstX[4], srow[4], scolu[4];
#pragma unroll
  for (int i = 0; i < 4; ++i) {
    int X = tid * 16 + i * 4096;
    int P = X ^ (((X >> 7) & 7) << 4);
    dstX[i] = X;
    srow[i] = P >> 7;
    scolu[i] = (P & 127) >> 1;
  }

  for (int k0 = 0; k0 < K; k0 += 64) {
    __syncthreads();
#pragma unroll
    for (int i = 0; i < 4; ++i) {
      const unsigned short* gA = A + (size_t)(m0 + srow[i]) * K + k0 + scolu[i];
      const unsigned short* gB = W + (size_t)(n0 + srow[i]) * K + k0 + scolu[i];
      __builtin_amdgcn_global_load_lds((const __attribute__((address_space(1))) void*)gA,
          (__attribute__((address_space(3))) void*)((char*)As + dstX[i]), 16, 0, 0);
      __builtin_amdgcn_global_load_lds((const __attribute__((address_space(1))) void*)gB,
          (__attribute__((address_space(3))) void*)((char*)Bs + dstX[i]), 16, 0, 0);
    }
    __syncthreads();
#pragma unroll
    for (int kk = 0; kk < 2; ++kk) {
      bf16x8 a[4], b[4];
#pragma unroll
      for (int m = 0; m < 4; ++m)
        a[m] = lds_read_sw64(As, wr + m * 16 + lr, kk * 32 + lk);
#pragma unroll
      for (int n = 0; n < 4; ++n)
        b[n] = lds_read_sw64(Bs, wc + n * 16 + lr, kk * 32 + lk);
#pragma unroll
      for (int m = 0; m < 4; ++m)
#pragma unroll
        for (int n = 0; n < 4; ++n)
          acc[m][n] = __builtin_amdgcn_mfma_f32_16x16x32_bf16(a[m], b[n], acc[m][n], 0, 0, 0);
    }
  }

  const int rbase = (lane >> 4) * 4;
  if (z == 2) {
#pragma unroll
    for (int m = 0; m < 4; ++m)
#pragma unroll
      for (int n = 0; n < 4; ++n) {
        int col = n0 + wc + n * 16 + lr;            // d-global
        float bvv = bias[col];
        int row0 = m0 + wr + m * 16 + rbase;        // s-global (4 consecutive)
        int bb = row0 >> 11, sr = row0 & 2047;
        int h = col >> 6, dk = col & 63;
        int kv32 = sr >> 5, half = (sr >> 4) & 1, hi5p = (sr >> 3) & 1, e0 = sr & 7;
        int dt = dk >> 5, qlp = dk & 31;
        u16x4 o;
#pragma unroll
        for (int r = 0; r < 4; ++r) o[r] = f2bf(acc[m][n][r] + bvv);
        size_t idx = ((((size_t)(bb * H_ + h) * 64 + kv32) * 2 + dt) * 2 + half) * 512
                     + (hi5p * 32 + qlp) * 8 + e0;
        *(u16x4*)(Vf + idx) = o;
      }
  } else {
    unsigned short* Cout = z == 0 ? Qf : Kf;
    const float scale = z == 0 ? QSCALE : 1.0f;
#pragma unroll
    for (int m = 0; m < 4; ++m)
#pragma unroll
      for (int n = 0; n < 4; ++n) {
        int col = n0 + wc + n * 16 + lr;            // s-global
        int drow0 = m0 + wr + m * 16 + rbase;       // d-global (4 consecutive)
        float4v bv4 = *(const float4v*)(bias + drow0);
        int h = drow0 >> 6, dk = drow0 & 63;
        int f = dk >> 4, hi5p = (dk >> 3) & 1, e0 = dk & 7;
        int bb = col >> 11, sr = col & 2047;
        int s32 = sr >> 5, qlp = sr & 31;
        u16x4 o;
#pragma unroll
        for (int r = 0; r < 4; ++r) o[r] = f2bf((acc[m][n][r] + bv4[r]) * scale);
        size_t base = (((size_t)(bb * H_ + h) * 64 + s32) * 4 + f) * 512
                      + (hi5p * 32 + qlp) * 8 + e0;
        *(u16x4*)(Cout + base) = o;
      }
  }
}

// ---------------------------- O GEMM (64x128 tile) -------------------------
__global__ __launch_bounds__(256) void gemm_o(const unsigned short* __restrict__ A,
                                              const unsigned short* __restrict__ W,
                                              const float* __restrict__ bias,
                                              float* __restrict__ C,
                                              int M, int N, int K) {
  __shared__ __align__(16) unsigned short As[64 * 64];
  __shared__ __align__(16) unsigned short Bs[128 * 64];
  const int tid  = threadIdx.x;
  const int lane = tid & 63;
  const int m0 = blockIdx.x * 64;
  const int n0 = blockIdx.y * 128;
  const int wr = ((tid >> 6) >> 1) * 32;
  const int wc = ((tid >> 6) & 1) * 64;
  const int lr = lane & 15;
  const int lk = (lane >> 4) * 8;
  f32x4 acc[2][4] = {};

  int dstX[4], srow[4], scolu[4];
#pragma unroll
  for (int i = 0; i < 4; ++i) {
    int X = tid * 16 + i * 4096;
    int P = X ^ (((X >> 7) & 7) << 4);
    dstX[i] = X;
    srow[i] = P >> 7;
    scolu[i] = (P & 127) >> 1;
  }

  for (int k0 = 0; k0 < K; k0 += 64) {
    __syncthreads();
#pragma unroll
    for (int i = 0; i < 2; ++i) {
      const unsigned short* gA = A + (size_t)(m0 + srow[i]) * K + k0 + scolu[i];
      __builtin_amdgcn_global_load_lds((const __attribute__((address_space(1))) void*)gA,
          (__attribute__((address_space(3))) void*)((char*)As + dstX[i]), 16, 0, 0);
    }
#pragma unroll
    for (int i = 0; i < 4; ++i) {
      const unsigned short* gB = W + (size_t)(n0 + srow[i]) * K + k0 + scolu[i];
      __builtin_amdgcn_global_load_lds((const __attribute__((address_space(1))) void*)gB,
          (__attribute__((address_space(3))) void*)((char*)Bs + dstX[i]), 16, 0, 0);
    }
    __syncthreads();
#pragma unroll
    for (int kk = 0; kk < 2; ++kk) {
      bf16x8 a[2], b[4];
#pragma unroll
      for (int m = 0; m < 2; ++m)
        a[m] = lds_read_sw64(As, wr + m * 16 + lr, kk * 32 + lk);
#pragma unroll
      for (int n = 0; n < 4; ++n)
        b[n] = lds_read_sw64(Bs, wc + n * 16 + lr, kk * 32 + lk);
#pragma unroll
      for (int m = 0; m < 2; ++m)
#pragma unroll
        for (int n = 0; n < 4; ++n)
          acc[m][n] = __builtin_amdgcn_mfma_f32_16x16x32_bf16(a[m], b[n], acc[m][n], 0, 0, 0);
    }
  }

  const int rbase = (lane >> 4) * 4;
#pragma unroll
  for (int m = 0; m < 2; ++m)
#pragma unroll
    for (int n = 0; n < 4; ++n) {
      int col = n0 + wc + n * 16 + lr;
      float bvv = bias[col];
#pragma unroll
      for (int r = 0; r < 4; ++r) {
        int row = m0 + wr + m * 16 + rbase + r;
        C[(size_t)row * N + col] = acc[m][n][r] + bvv;
      }
    }
}

// ---------------------------- flash attention (reg, FROZEN R18) ------------
// Grid: (32, H, B), 256 threads = 4 waves. Block owns paired q-slices
// (63-bx, bx), 32 q-rows each. Wave kq processes kv windows w == kq (mod 4),
// loading K/V fragments as coalesced b128 from fragment-major Kf/Vf.
__global__ __launch_bounds__(256, 4) void flash_reg(const unsigned short* __restrict__ Qf,
                                                    const unsigned short* __restrict__ Kf,
                                                    const unsigned short* __restrict__ Vf,
                                                    unsigned short* __restrict__ Op) {
  __shared__ float scr[3 * 64 * 34];   // 26112 B merge scratch

  const int tid  = threadIdx.x;
  const int lane = tid & 63;
  const int kq   = tid >> 6;
  const int bx = blockIdx.x;
  const int h  = blockIdx.y;
  const int b  = blockIdx.z;
  const int ql = lane & 31;
  const int hi5 = lane >> 5;
  const int bh = b * H_ + h;
  const size_t basebs = (size_t)b * S_ * D_;
  const int hoff = h * DK_;

  const unsigned short* Qb = Qf + (size_t)bh * 131072 + lane * 8;
  const unsigned short* Kb = Kf + (size_t)bh * 131072 + lane * 8;
  const unsigned short* Vb = Vf + (size_t)bh * 131072 + lane * 8;

  for (int s = 0; s < 2; ++s) {
    const int j = s == 0 ? 63 - bx : bx;   // q-slice index (32 rows)
    const int q0 = j * 32;
    const int qglob = q0 + ql;

    bf16x8 qf4[4];
    {
      const unsigned short* qp_ = Qb + (size_t)j * 2048;
#pragma unroll
      for (int f = 0; f < 4; ++f) qf4[f] = *(const bf16x8*)(qp_ + f * 512);
    }

    float m_r = -1e30f;
    float l_r = 0.f;
    f32x16 out0 = {};   // d = (g&3)+8*(g>>2)+4*hi5
    f32x16 out1 = {};   // d = 32 + same

    for (int w = kq; w <= j; w += 4) {
      const unsigned short* kp_ = Kb + (size_t)w * 2048;
      bf16x8 kf0 = *(const bf16x8*)(kp_);
      bf16x8 kf1 = *(const bf16x8*)(kp_ + 512);
      bf16x8 kf2 = *(const bf16x8*)(kp_ + 1024);
      bf16x8 kf3 = *(const bf16x8*)(kp_ + 1536);

      f32x16 sc = {};
      __builtin_amdgcn_s_setprio(1);
      sc = __builtin_amdgcn_mfma_f32_32x32x16_bf16(kf0, qf4[0], sc, 0, 0, 0);
      sc = __builtin_amdgcn_mfma_f32_32x32x16_bf16(kf1, qf4[1], sc, 0, 0, 0);
      sc = __builtin_amdgcn_mfma_f32_32x32x16_bf16(kf2, qf4[2], sc, 0, 0, 0);
      sc = __builtin_amdgcn_mfma_f32_32x32x16_bf16(kf3, qf4[3], sc, 0, 0, 0);
      __builtin_amdgcn_s_setprio(0);

      // V fragment loads issued early: latency hides under softmax
      const unsigned short* vp_ = Vb + (size_t)w * 2048;
      bf16x8 vf00 = *(const bf16x8*)(vp_);          // dt0 half0
      bf16x8 vf01 = *(const bf16x8*)(vp_ + 512);    // dt0 half1
      bf16x8 vf10 = *(const bf16x8*)(vp_ + 1024);   // dt1 half0
      bf16x8 vf11 = *(const bf16x8*)(vp_ + 1536);   // dt1 half1

      if (w == j) {   // diagonal: causal mask
#pragma unroll
        for (int g = 0; g < 16; ++g) {
          int kvg = w * 32 + (g & 3) + 8 * (g >> 2) + 4 * hi5;
          if (kvg > qglob) sc[g] = -1e30f;
        }
      }

      float pm = sc[0];
#pragma unroll
      for (int g = 1; g < 16; ++g) pm = fmaxf(pm, sc[g]);
      pm = fmaxf(pm, partner32f(pm, hi5));

      if (!__all(pm - m_r <= 8.0f)) {   // defer-max (2^8 headroom)
        float mnew = fmaxf(m_r, pm);
        float scl = __builtin_exp2f(m_r - mnew);
        l_r *= scl;
#pragma unroll
        for (int g = 0; g < 16; ++g) { out0[g] *= scl; out1[g] *= scl; }
        m_r = mnew;
      }

      float l_add = 0.f;
#define PV_HALF(HALF, VF0, VF1)                                                \
      {                                                                        \
        const int g0 = (HALF) * 8;                                             \
        float p0 = __builtin_exp2f(sc[g0 + 0] - m_r);                          \
        float p1 = __builtin_exp2f(sc[g0 + 1] - m_r);                          \
        float p2 = __builtin_exp2f(sc[g0 + 2] - m_r);                          \
        float p3 = __builtin_exp2f(sc[g0 + 3] - m_r);                          \
        float p4 = __builtin_exp2f(sc[g0 + 4] - m_r);                          \
        float p5 = __builtin_exp2f(sc[g0 + 5] - m_r);                          \
        float p6 = __builtin_exp2f(sc[g0 + 6] - m_r);                          \
        float p7 = __builtin_exp2f(sc[g0 + 7] - m_r);                          \
        l_add += ((p0 + p1) + (p2 + p3)) + ((p4 + p5) + (p6 + p7));            \
        unsigned int u0 = cvt_pk_bf16(p0, p1);                                 \
        unsigned int u1 = cvt_pk_bf16(p2, p3);                                 \
        unsigned int u2 = cvt_pk_bf16(p4, p5);                                 \
        unsigned int u3 = cvt_pk_bf16(p6, p7);                                 \
        unsigned int ta = hi5 ? u0 : u2, tb = hi5 ? u1 : u3;                   \
        unsigned int ra = partner32u(ta, hi5);                                 \
        unsigned int rb = partner32u(tb, hi5);                                 \
        u32x4 pw = {hi5 ? ra : u0, hi5 ? rb : u1,                              \
                    hi5 ? u2 : ra, hi5 ? u3 : rb};                             \
        bf16x8 pf = __builtin_bit_cast(bf16x8, pw);                            \
        out0 = __builtin_amdgcn_mfma_f32_32x32x16_bf16(VF0, pf, out0, 0, 0, 0);\
        out1 = __builtin_amdgcn_mfma_f32_32x32x16_bf16(VF1, pf, out1, 0, 0, 0);\
      }
      __builtin_amdgcn_s_setprio(1);
      PV_HALF(0, vf00, vf10);
      PV_HALF(1, vf01, vf11);
      __builtin_amdgcn_s_setprio(0);
#undef PV_HALF

      l_add += partner32f(l_add, hi5);
      l_r += l_add;
    }

    // ---- merge the 4 kv-quarter partials ----
    __syncthreads();
    if (kq != 0) {
      float* p = scr + ((size_t)(kq - 1) * 64 + lane) * 34;
#pragma unroll
      for (int g = 0; g < 16; ++g) { p[g] = out0[g]; p[16 + g] = out1[g]; }
      p[32] = m_r;
      p[33] = l_r;
    }
    __syncthreads();
    if (kq == 0) {
      float mA = m_r, lA = l_r;
#pragma unroll
      for (int j3 = 0; j3 < 3; ++j3) {
        const float* p = scr + ((size_t)j3 * 64 + lane) * 34;
        float mj = p[32], lj = p[33];
        float mM = fmaxf(mA, mj);
        float s0 = __builtin_exp2f(mA - mM);
        float s1 = __builtin_exp2f(mj - mM);
#pragma unroll
        for (int g = 0; g < 16; ++g) {
          out0[g] = out0[g] * s0 + p[g] * s1;
          out1[g] = out1[g] * s0 + p[16 + g] * s1;
        }
        lA = lA * s0 + lj * s1;
        mA = mM;
      }
      float rcp = 1.0f / lA;
      unsigned short* orow = Op + basebs + (size_t)qglob * D_ + hoff;
#pragma unroll
      for (int i = 0; i < 4; ++i) {
        u32x2 o0 = {cvt_pk_bf16(out0[4 * i + 0] * rcp, out0[4 * i + 1] * rcp),
                    cvt_pk_bf16(out0[4 * i + 2] * rcp, out0[4 * i + 3] * rcp)};
        *(u32x2*)(orow + 8 * i + 4 * hi5) = o0;
        u32x2 o1 = {cvt_pk_bf16(out1[4 * i + 0] * rcp, out1[4 * i + 1] * rcp),
                    cvt_pk_bf16(out1[4 * i + 2] * rcp, out1[4 * i + 3] * rcp)};
        *(u32x2*)(orow + 32 + 8 * i + 4 * hi5) = o1;
      }
    }
    __syncthreads();   // scratch reads done before next slice's writes
  }
}

// ---------------------------- launch ---------------------------------------
extern "C" void kernel_launch(void* const* d_in, const int* in_sizes, int n_in,
                              void* d_out, int out_size, void* d_ws, size_t ws_size,
                              hipStream_t stream) {
  const float* q  = (const float*)d_in[0];
  const float* k  = (const float*)d_in[1];
  const float* v  = (const float*)d_in[2];
  // d_in[3] = causal mask (tril) -- semantics hard-coded in flash_reg
  const float* Wq = (const float*)d_in[4];
  const float* bq = (const float*)d_in[5];
  const float* Wk = (const float*)d_in[6];
  const float* bk = (const float*)d_in[7];
  const float* Wv = (const float*)d_in[8];
  const float* bv = (const float*)d_in[9];
  const float* Wo = (const float*)d_in[10];
  const float* bo = (const float*)d_in[11];

  const int MSD = B_ * S_;     // 4096 rows
  unsigned short* ws = (unsigned short*)d_ws;
  unsigned short* Xq  = ws;
  unsigned short* Xk  = Xq  + (size_t)MSD * D_;
  unsigned short* Xv  = Xk  + (size_t)MSD * D_;
  unsigned short* Wqb = Xv  + (size_t)MSD * D_;
  unsigned short* Wkb = Wqb + (size_t)D_ * D_;
  unsigned short* Wvb = Wkb + (size_t)D_ * D_;
  unsigned short* Wob = Wvb + (size_t)D_ * D_;
  unsigned short* Qf  = Wob + (size_t)D_ * D_;   // fragment-major layouts
  unsigned short* Kf  = Qf  + (size_t)MSD * D_;
  unsigned short* Vf  = Kf  + (size_t)MSD * D_;
  unsigned short* At  = Vf  + (size_t)MSD * D_;  // attention out, row-major

  cvt_all<<<16384, 256, 0, stream>>>(q, k, v, Wq, Wk, Wv, Wo,
                                     Xq, Xk, Xv, Wqb, Wkb, Wvb, Wob);

  dim3 gqkv(MSD / 128, D_ / 128, 3);   // (32, 8, 3) = 768 blocks
  gemm_qkv<<<gqkv, 256, 0, stream>>>(Xq, Xk, Xv, Wqb, Wkb, Wvb,
                                     bq, bk, bv, Qf, Kf, Vf);

  dim3 ga(32, H_, B_);                 // 1024 blocks x 4 waves, paired slices
  flash_reg<<<ga, 256, 0, stream>>>(Qf, Kf, Vf, At);

  dim3 go(MSD / 64, D_ / 128);         // (64, 8) = 512 blocks
  gemm_o<<<go, 256, 0, stream>>>(At, Wob, bo, (float*)d_out, MSD, D_, D_);
}